// Round 2
// baseline (46.314 us; speedup 1.0000x reference)
//
#include <hip/hip_runtime.h>
#include <math.h>

#define BB 64
#define AA 32
#define KK 50
#define DD 128
#define MAX_KP 50
#define EPS_CS 1e-8f
#define NVEC (3 * BB * AA)   // 6144
#define VPB 8                // vectors per 256-thread block (32 lanes each)

__device__ __forceinline__ float dot4(float4 a, float4 b) {
    return a.x * b.x + a.y * b.y + a.z * b.z + a.w * b.w;
}

// 256 threads = 8 vectors/block, 32 lanes per vector (float4 per lane).
// Gather K=50 rows (16B/lane), mean-pool, L2-normalize, write to ws.
__global__ __launch_bounds__(256) void embed_norm_kernel(
    const int* __restrict__ src, const int* __restrict__ pos,
    const int* __restrict__ neg, const float* __restrict__ table,
    float* __restrict__ out, unsigned* __restrict__ counter)
{
    if (blockIdx.x == 0 && threadIdx.x == 0) *counter = 0u;  // for loss tail

    const int tid  = threadIdx.x;
    const int lane = tid & 31;                 // float4 slot within row
    const int vec  = blockIdx.x * VPB + (tid >> 5);
    const int t    = vec >> 11;                // / (BB*AA)
    const int ba   = vec & 2047;
    const int* idx = ((t == 0) ? src : (t == 1) ? pos : neg) + ba * KK;

    // preload the 50 indices into 2 registers per lane-group
    int i0 = idx[lane];                        // idx[0..31]
    int i1 = (lane < (KK - 32)) ? idx[32 + lane] : 0;  // idx[32..49]

    const float4* tab4 = (const float4*)table;
    float4 acc = make_float4(0.f, 0.f, 0.f, 0.f);
    #pragma unroll
    for (int k = 0; k < 32; ++k) {
        const int row = __shfl(i0, k, 32);     // broadcast within 32-lane group
        const float4 v = tab4[row * 32 + lane];
        acc.x += v.x; acc.y += v.y; acc.z += v.z; acc.w += v.w;
    }
    #pragma unroll
    for (int k = 0; k < KK - 32; ++k) {
        const int row = __shfl(i1, k, 32);
        const float4 v = tab4[row * 32 + lane];
        acc.x += v.x; acc.y += v.y; acc.z += v.z; acc.w += v.w;
    }

    const float s = 1.0f / MAX_KP;
    acc.x *= s; acc.y *= s; acc.z *= s; acc.w *= s;

    float sq = dot4(acc, acc);
    #pragma unroll
    for (int off = 16; off > 0; off >>= 1) sq += __shfl_xor(sq, off, 32);

    const float inv = 1.0f / fmaxf(sqrtf(sq), EPS_CS);
    acc.x *= inv; acc.y *= inv; acc.z *= inv; acc.w *= inv;

    ((float4*)out)[vec * 32 + lane] = acc;
}

// One block per batch. LDS-staged src/pos/neg (rows padded to 132 floats:
// keeps 16B alignment for b128 reads; start-bank shift of 4 per row ->
// <=2-way conflicts, free). Each thread: 2x2 (i,j) tile for pos AND neg.
// Last block (agent-scope counter) computes the mean loss into d_out.
__global__ __launch_bounds__(256) void cosine_loss_kernel(
    const float* __restrict__ embs, float* __restrict__ per_batch,
    unsigned* __restrict__ counter, float* __restrict__ out)
{
    const int b   = blockIdx.x;
    const int tid = threadIdx.x;

    __shared__ float s_src[AA][DD + 4];
    __shared__ float s_pos[AA][DD + 4];
    __shared__ float s_neg[AA][DD + 4];

    const float4* src4 = (const float4*)(embs + (long)b * AA * DD);
    const float4* pos4 = (const float4*)(embs + (long)(BB + b) * AA * DD);
    const float4* neg4 = (const float4*)(embs + (long)(2 * BB + b) * AA * DD);

    for (int i = tid; i < AA * DD / 4; i += 256) {   // 1024 float4s
        const int r = i >> 5, c = i & 31;
        *(float4*)&s_src[r][c * 4] = src4[i];
        *(float4*)&s_pos[r][c * 4] = pos4[i];
        *(float4*)&s_neg[r][c * 4] = neg4[i];
    }
    __syncthreads();

    const int ib = tid >> 4;     // 0..15 ; rows ib, ib+16
    const int jb = tid & 15;     // 0..15 ; cols jb, jb+16

    float dp00 = 0, dp01 = 0, dp10 = 0, dp11 = 0;
    float dn00 = 0, dn01 = 0, dn10 = 0, dn11 = 0;
    #pragma unroll 8
    for (int d0 = 0; d0 < DD; d0 += 4) {
        const float4 a0 = *(const float4*)&s_src[ib][d0];
        const float4 a1 = *(const float4*)&s_src[ib + 16][d0];
        const float4 p0 = *(const float4*)&s_pos[jb][d0];
        const float4 p1 = *(const float4*)&s_pos[jb + 16][d0];
        const float4 n0 = *(const float4*)&s_neg[jb][d0];
        const float4 n1 = *(const float4*)&s_neg[jb + 16][d0];
        dp00 += dot4(a0, p0); dp01 += dot4(a0, p1);
        dp10 += dot4(a1, p0); dp11 += dot4(a1, p1);
        dn00 += dot4(a0, n0); dn01 += dot4(a0, n1);
        dn10 += dot4(a1, n0); dn11 += dot4(a1, n1);
    }

    float pmax = fmaxf(fmaxf(dp00, dp01), fmaxf(dp10, dp11));
    float nmax = fmaxf(fmaxf(dn00, dn01), fmaxf(dn10, dn11));

    #pragma unroll
    for (int off = 32; off > 0; off >>= 1) {
        pmax = fmaxf(pmax, __shfl_xor(pmax, off, 64));
        nmax = fmaxf(nmax, __shfl_xor(nmax, off, 64));
    }
    __shared__ float sp[4], sn[4];
    const int wave = tid >> 6;
    if ((tid & 63) == 0) { sp[wave] = pmax; sn[wave] = nmax; }
    __syncthreads();

    if (tid == 0) {
        const float P = fmaxf(fmaxf(sp[0], sp[1]), fmaxf(sp[2], sp[3]));
        const float N = fmaxf(fmaxf(sn[0], sn[1]), fmaxf(sn[2], sn[3]));
        const float x = P - N;
        const float l = (x >= 0.f) ? log1pf(expf(-x)) : (-x + log1pf(expf(x)));

        __hip_atomic_store(&per_batch[b], l, __ATOMIC_RELEASE,
                           __HIP_MEMORY_SCOPE_AGENT);
        const unsigned old = __hip_atomic_fetch_add(
            counter, 1u, __ATOMIC_ACQ_REL, __HIP_MEMORY_SCOPE_AGENT);
        if (old == BB - 1) {   // last block: fixed-order sum -> deterministic
            float acc = 0.f;
            for (int i = 0; i < BB; ++i)
                acc += __hip_atomic_load(&per_batch[i], __ATOMIC_ACQUIRE,
                                         __HIP_MEMORY_SCOPE_AGENT);
            out[0] = acc * (1.0f / BB);
            __hip_atomic_store(counter, 0u, __ATOMIC_RELAXED,
                               __HIP_MEMORY_SCOPE_AGENT);
        }
    }
}

extern "C" void kernel_launch(void* const* d_in, const int* in_sizes, int n_in,
                              void* d_out, int out_size, void* d_ws, size_t ws_size,
                              hipStream_t stream) {
    const int*   batch_source = (const int*)d_in[0];
    const int*   pos_result   = (const int*)d_in[1];
    const int*   neg_result   = (const int*)d_in[2];
    const float* emb_table    = (const float*)d_in[3];
    float* out = (float*)d_out;

    float*    embs      = (float*)d_ws;                  // 3*64*32*128 f32 = 3 MB
    float*    per_batch = embs + 3L * BB * AA * DD;      // 64 f32
    unsigned* counter   = (unsigned*)(per_batch + BB);   // 1 u32

    embed_norm_kernel<<<NVEC / VPB, 256, 0, stream>>>(
        batch_source, pos_result, neg_result, emb_table, embs, counter);
    cosine_loss_kernel<<<BB, 256, 0, stream>>>(embs, per_batch, counter, out);
}